// Round 9
// baseline (3334.398 us; speedup 1.0000x reference)
//
#include <hip/hip_runtime.h>

// ============================================================================
// 2-layer tanh RNN (B=128,S=512,IN=128,H=512) + linear head (C=1000) + logsoftmax
//
// Round-9: dual batch-group phase-interleaved i8 recurrence.
//   R8 lesson: barrier-locked sibling waves can't fill each other's bubbles.
//   Fix: ONE instruction stream per wave handles TWO independent batch-groups
//   a half-step out of phase — group A's epilogue VALU issues while group B's
//   MFMAs/loads are in flight, and vice versa. 4 WGs x 256 thr (1 wave/SIMD).
//   - W_hh i8 per-row scale, fully resident: kt0..6 in 224 AGPRs, kt7 in 32
//     VGPRs (pinned; R3/R4/R5 lessons).
//   - h state per group: i8 LDS [2][16][512] dbuf (32 KB total), XOR-lm
//     16B-granule swizzle. lgkmcnt-only barrier (2 per step).
//   - xp pre-scaled by 2*log2(e) at proj epilogue; sc2 absorbs the factor ->
//     epilogue per value = cvt+fma+exp2+add+rcp+fma (4 VALU + 2 trans).
//   - xv loaded a half-step before use.
//
// ws layout: bufA = ws (64 MB): xp0/hs0 in place; later Wq1 head + hlast @
//            +1MB. bufB = ws+64MB: Wq0/sc0 head (dead after rec0), later xp1.
// ============================================================================

using short8  = __attribute__((ext_vector_type(8))) short;
using floatx4 = __attribute__((ext_vector_type(4))) float;
using i32x4   = __attribute__((ext_vector_type(4))) int;
using f32x4   = __attribute__((ext_vector_type(4))) float;

#define DEV static __device__ __forceinline__
#define PINA(x) asm volatile("" : "+a"(x))
#define PINV(x) asm volatile("" : "+v"(x))

#define TWO_LOG2E 2.8853900817779268f

DEV void lds_barrier() {
    // LDS-only barrier: do NOT drain vmcnt (global stores/loads keep flying).
    asm volatile("s_waitcnt lgkmcnt(0)\n\ts_barrier" ::: "memory");
}

DEV unsigned short f2bf(float f) {
    union { float f; unsigned u; } v; v.f = f;
    unsigned r = (v.u + 0x7fffu + ((v.u >> 16) & 1u)) >> 16;
    return (unsigned short)r;
}

// ---------------------------------------------------------------------------
// packi8: one block (64 thr) per W row j. Row absmax -> per-row scale;
// quantize to i8 in A-frag layout for mfma_i32_16x16x64_i8.
// sc2[j] = mx_j / 127^2 * 2*log2(e)  (dequant folded into exp2 argument).
// ---------------------------------------------------------------------------
__global__ __launch_bounds__(64) void packi8_kernel(
    const float* __restrict__ W, signed char* __restrict__ Wq,
    float* __restrict__ sc2)
{
    const int j = blockIdx.x;            // 0..511
    const int t = threadIdx.x;           // 0..63
    const float* row = W + (size_t)j * 512;

    float4 a = *(const float4*)(row + t * 8);
    float4 b = *(const float4*)(row + t * 8 + 4);
    float m = fmaxf(fmaxf(fabsf(a.x), fabsf(a.y)), fmaxf(fabsf(a.z), fabsf(a.w)));
    m = fmaxf(m, fmaxf(fmaxf(fabsf(b.x), fabsf(b.y)), fmaxf(fabsf(b.z), fabsf(b.w))));
    #pragma unroll
    for (int off = 32; off; off >>= 1) m = fmaxf(m, __shfl_down(m, off, 64));
    m = __shfl(m, 0, 64);
    if (t == 0) sc2[j] = m * (1.0f / (127.f * 127.f)) * TWO_LOG2E;

    if (t < 32) {
        const int kt = t >> 2, lq = t & 3;
        const int jtg = j >> 4, lm = j & 15;
        const float r = 127.f / m;
        int w4[4];
        #pragma unroll
        for (int w = 0; w < 4; ++w) {
            int v = 0;
            #pragma unroll
            for (int e = 0; e < 4; ++e) {
                int q = __float2int_rn(row[kt * 64 + lq * 16 + w * 4 + e] * r);
                v |= (q & 255) << (8 * e);
            }
            w4[w] = v;
        }
        i32x4 pk; pk[0] = w4[0]; pk[1] = w4[1]; pk[2] = w4[2]; pk[3] = w4[3];
        *(i32x4*)(Wq + ((size_t)((jtg * 8 + kt) * 64 + lq * 16 + lm)) * 16) = pk;
    }
}

// ---------------------------------------------------------------------------
// proj: out[m=t*128+b][n] = bf16( (A[m][:]·W[n][:] + b1[n]+b2[n]) * oscale )
// oscale = 2*log2(e): rec consumes xp only inside exp2 arguments.
// ---------------------------------------------------------------------------
template <int K, int MODE>
__global__ __launch_bounds__(256, 2) void proj_kernel(
    const void* __restrict__ Aptr, const float* __restrict__ W,
    const float* __restrict__ b1, const float* __restrict__ b2,
    unsigned short* __restrict__ out, float oscale)
{
    constexpr int LDA = 40;
    __shared__ unsigned short As[128 * LDA];
    __shared__ unsigned short Ws[64 * LDA];

    const int tid  = threadIdx.x;
    const int lane = tid & 63, wave = tid >> 6;
    const int lm   = lane & 15, lq = lane >> 4;
    const int nbase = blockIdx.x * 64;
    const int mtile = blockIdx.y;
    const int mbase = mtile * 128;

    floatx4 acc[2][4] = {};

    const int ar = tid >> 1, ak = (tid & 1) * 16;
    const int wr = tid >> 2, wk = (tid & 3) * 8;

    for (int k0 = 0; k0 < K; k0 += 32) {
        if (MODE == 0) {
            const float* x   = (const float*)Aptr;
            const float* src = x + ((size_t)ar * 512 + mtile) * 128 + (k0 + ak);
            float4 f0 = *(const float4*)(src + 0);
            float4 f1 = *(const float4*)(src + 4);
            float4 f2 = *(const float4*)(src + 8);
            float4 f3 = *(const float4*)(src + 12);
            unsigned short* d = As + ar * LDA + ak;
            d[0]=f2bf(f0.x); d[1]=f2bf(f0.y); d[2]=f2bf(f0.z); d[3]=f2bf(f0.w);
            d[4]=f2bf(f1.x); d[5]=f2bf(f1.y); d[6]=f2bf(f1.z); d[7]=f2bf(f1.w);
            d[8]=f2bf(f2.x); d[9]=f2bf(f2.y); d[10]=f2bf(f2.z); d[11]=f2bf(f2.w);
            d[12]=f2bf(f3.x); d[13]=f2bf(f3.y); d[14]=f2bf(f3.z); d[15]=f2bf(f3.w);
        } else {
            const unsigned short* h =
                (const unsigned short*)Aptr + (size_t)(mbase + ar) * K + k0 + ak;
            short8 v0 = *(const short8*)(h);
            short8 v1 = *(const short8*)(h + 8);
            *(short8*)(As + ar * LDA + ak)     = v0;
            *(short8*)(As + ar * LDA + ak + 8) = v1;
        }
        {
            const float* src = W + (size_t)(nbase + wr) * K + k0 + wk;
            float4 f0 = *(const float4*)(src);
            float4 f1 = *(const float4*)(src + 4);
            unsigned short* d = Ws + wr * LDA + wk;
            d[0]=f2bf(f0.x); d[1]=f2bf(f0.y); d[2]=f2bf(f0.z); d[3]=f2bf(f0.w);
            d[4]=f2bf(f1.x); d[5]=f2bf(f1.y); d[6]=f2bf(f1.z); d[7]=f2bf(f1.w);
        }
        __syncthreads();

        short8 af0 = *(const short8*)(As + (wave * 32 +  0 + lm) * LDA + lq * 8);
        short8 af1 = *(const short8*)(As + (wave * 32 + 16 + lm) * LDA + lq * 8);
        #pragma unroll
        for (int nt = 0; nt < 4; ++nt) {
            short8 bf = *(const short8*)(Ws + (nt * 16 + lm) * LDA + lq * 8);
            acc[0][nt] = __builtin_amdgcn_mfma_f32_16x16x32_bf16(af0, bf, acc[0][nt], 0, 0, 0);
            acc[1][nt] = __builtin_amdgcn_mfma_f32_16x16x32_bf16(af1, bf, acc[1][nt], 0, 0, 0);
        }
        __syncthreads();
    }

    #pragma unroll
    for (int nt = 0; nt < 4; ++nt) {
        const int n = nbase + nt * 16 + lm;
        const float bias = b1[n] + b2[n];
        #pragma unroll
        for (int mt = 0; mt < 2; ++mt) {
            const int mrow = mbase + wave * 32 + mt * 16 + lq * 4;
            #pragma unroll
            for (int r = 0; r < 4; ++r)
                out[(size_t)(mrow + r) * 512 + n] = f2bf((acc[mt][nt][r] + bias) * oscale);
        }
    }
}

// ---------------------------------------------------------------------------
// rec9: 4 WGs x 256 thr (4 waves, 1/SIMD). WG bg owns batch-groups A = 2bg,
// B = 2bg+1 (32 batches). Wave owns 8 j-tiles for BOTH groups (W shared).
// Phase-interleaved halves; 2 lgkmcnt barriers per step.
// MODE 0: store h_t bf16 to hs_out (in-place over xp). MODE 1: t=511 -> h_last.
// ---------------------------------------------------------------------------

// epilogue for one group's step-t values (acc + scaled-xv -> tanh -> i8 LDS
// (+ optional global stores)). XV holds xp pre-scaled by 2*log2(e) in bf16.
#define EPI_GROUP(ACC, XV, HW, HST, HL)                                          \
  do {                                                                           \
    _Pragma("unroll")                                                            \
    for (int j = 0; j < 8; ++j) {                                                \
      const int jtg = wave * 8 + j;                                              \
      float x0 = __uint_as_float(__builtin_amdgcn_perm(XV[j].x, 0u, 0x05040c0cu)); \
      float x1 = __uint_as_float(__builtin_amdgcn_perm(XV[j].x, 0u, 0x07060c0cu)); \
      float x2 = __uint_as_float(__builtin_amdgcn_perm(XV[j].y, 0u, 0x05040c0cu)); \
      float x3 = __uint_as_float(__builtin_amdgcn_perm(XV[j].y, 0u, 0x07060c0cu)); \
      float e0 = __builtin_amdgcn_exp2f(fmaf((float)ACC[j][0], sc[j][0], x0));   \
      float e1 = __builtin_amdgcn_exp2f(fmaf((float)ACC[j][1], sc[j][1], x1));   \
      float e2 = __builtin_amdgcn_exp2f(fmaf((float)ACC[j][2], sc[j][2], x2));   \
      float e3 = __builtin_amdgcn_exp2f(fmaf((float)ACC[j][3], sc[j][3], x3));   \
      float q0 = fmaf(-2.f, __builtin_amdgcn_rcpf(e0 + 1.f), 1.f);               \
      float q1 = fmaf(-2.f, __builtin_amdgcn_rcpf(e1 + 1.f), 1.f);               \
      float q2 = fmaf(-2.f, __builtin_amdgcn_rcpf(e2 + 1.f), 1.f);               \
      float q3 = fmaf(-2.f, __builtin_amdgcn_rcpf(e3 + 1.f), 1.f);               \
      unsigned m0 = __float_as_uint(fmaf(q0, 127.f, 12582912.f));                \
      unsigned m1 = __float_as_uint(fmaf(q1, 127.f, 12582912.f));                \
      unsigned m2 = __float_as_uint(fmaf(q2, 127.f, 12582912.f));                \
      unsigned m3 = __float_as_uint(fmaf(q3, 127.f, 12582912.f));                \
      unsigned lo = __builtin_amdgcn_perm(m1, m0, 0x00000400u);                  \
      unsigned hi = __builtin_amdgcn_perm(m3, m2, 0x00000400u);                  \
      unsigned qb = __builtin_amdgcn_perm(hi, lo, 0x05040100u);                  \
      *(unsigned*)((HW) + lm * 512 + ((jtg ^ lm) << 4) + lq * 4) = qb;           \
      if (MODE == 0) {                                                           \
        uint2 st;                                                                \
        st.x = __builtin_amdgcn_perm(__float_as_uint(q1), __float_as_uint(q0), 0x07060302u); \
        st.y = __builtin_amdgcn_perm(__float_as_uint(q3), __float_as_uint(q2), 0x07060302u); \
        *(uint2*)((HST) + j * 16) = st;                                          \
      } else if (HL) {                                                           \
        float4 o; o.x = q0; o.y = q1; o.z = q2; o.w = q3;                        \
        *(float4*)((HL) + jtg * 16 + lq * 4) = o;                                \
      }                                                                          \
    }                                                                            \
  } while (0)

template <int MODE>
__global__ __launch_bounds__(256, 1) void rec9_kernel(
    const signed char* __restrict__ Wq,   // [32 jtg][8 kt][64 lane][16] i8
    const float* __restrict__ sc2,        // [512] row scale * 2log2e / 127^2
    const unsigned short* xp,             // [S][B][H] bf16 SCALED (aliases hs_out)
    unsigned short* hs_out,               // [S][B][H] bf16
    float* __restrict__ h_last)           // [B][H] fp32
{
    __shared__ unsigned char h2[2][2][16 * 512];   // [group][slot], 32 KB

    const int tid  = threadIdx.x;
    const int lane = tid & 63;
    const int wave = tid >> 6;              // 0..3
    const int lm   = lane & 15, lq = lane >> 4;
    const int bg   = blockIdx.x;            // 0..3
    const int bbA  = bg * 32 + lm;
    const int bbB  = bbA + 16;

    // ---- W slice: kt0..6 in AGPRs (224), kt7 in VGPRs (32); pinned ----
    i32x4 wa[8][7], wv[8];
    #pragma unroll
    for (int j = 0; j < 8; ++j) {
        const int jtg = wave * 8 + j;
        #pragma unroll
        for (int kt = 0; kt < 7; ++kt)
            wa[j][kt] = *(const i32x4*)(Wq + ((size_t)((jtg * 8 + kt) * 64 + lane)) * 16);
        wv[j] = *(const i32x4*)(Wq + ((size_t)((jtg * 8 + 7) * 64 + lane)) * 16);
    }
    #pragma unroll
    for (int j = 0; j < 8; ++j) {
        #pragma unroll
        for (int kt = 0; kt < 7; ++kt) PINA(wa[j][kt]);
        PINV(wv[j]);
    }

    // ---- per-lane fused dequant scales ----
    f32x4 sc[8];
    #pragma unroll
    for (int j = 0; j < 8; ++j)
        sc[j] = *(const f32x4*)(sc2 + (wave * 8 + j) * 16 + lq * 4);
    #pragma unroll
    for (int j = 0; j < 8; ++j) PINV(sc[j]);

    // ---- zero h buffers (32 KB) ----
    for (int i = tid; i < 8192; i += 256) ((int*)h2)[i] = 0;
    __syncthreads();

    // per-thread streaming pointers (row stride 128*512 elems per step)
    const unsigned short* xptA = xp + (size_t)bbA * 512 + wave * 128 + lq * 4;
    const unsigned short* xptB = xp + (size_t)bbB * 512 + wave * 128 + lq * 4;
    unsigned short* hstA = hs_out + (size_t)bbA * 512 + wave * 128 + lq * 4;
    unsigned short* hstB = hs_out + (size_t)bbB * 512 + wave * 128 + lq * 4;

    uint2 xvA[8], xvB[8];
    i32x4 accA[8], accB[8];
    const i32x4 z4 = {0, 0, 0, 0};

    // ---- prologue: h_A(-1)=0 -> accA(0)=0; prefetch xv_A(0) ----
    #pragma unroll
    for (int j = 0; j < 8; ++j) xvA[j] = *(const uint2*)(xptA + j * 16);
    xptA += 65536;
    #pragma unroll
    for (int j = 0; j < 8; ++j) accA[j] = z4;

    for (int t = 0; t < 512; ++t) {
        // ================= half 2: epi_A(t) + MFMA_B(t) =================
        #pragma unroll
        for (int j = 0; j < 8; ++j) xvB[j] = *(const uint2*)(xptB + j * 16);
        xptB += 65536;

        i32x4 bfr[8];
        {
            unsigned char* hp = &h2[1][t & 1][0];        // h_B(t-1)
            #pragma unroll
            for (int kt = 0; kt < 8; ++kt)
                bfr[kt] = *(const i32x4*)(hp + lm * 512 + (((kt << 2) + lq) ^ lm) * 16);
        }
        {
            unsigned char* hwA = &h2[0][(t + 1) & 1][0];
            float* hlA = (MODE == 1 && t == 511) ? (h_last + (size_t)bbA * 512) : (float*)0;
            EPI_GROUP(accA, xvA, hwA, hstA, hlA);
            hstA += 65536;
        }
        #pragma unroll
        for (int j = 0; j < 8; ++j) {
            accB[j] = __builtin_amdgcn_mfma_i32_16x16x64_i8(wa[j][0], bfr[0], z4, 0, 0, 0);
            #pragma unroll
            for (int kt = 1; kt < 7; ++kt)
                accB[j] = __builtin_amdgcn_mfma_i32_16x16x64_i8(wa[j][kt], bfr[kt], accB[j], 0, 0, 0);
            accB[j] = __builtin_amdgcn_mfma_i32_16x16x64_i8(wv[j], bfr[7], accB[j], 0, 0, 0);
        }
        lds_barrier();

        // ============== half 1 of t+1: epi_B(t) + MFMA_A(t+1) ==============
        if (t < 511) {
            #pragma unroll
            for (int j = 0; j < 8; ++j) xvA[j] = *(const uint2*)(xptA + j * 16);
            xptA += 65536;

            {
                unsigned char* hp = &h2[0][(t + 1) & 1][0];   // h_A(t)
                #pragma unroll
                for (int kt = 0; kt < 8; ++kt)
                    bfr[kt] = *(const i32x4*)(hp + lm * 512 + (((kt << 2) + lq) ^ lm) * 16);
            }
            {
                unsigned char* hwB = &h2[1][(t + 1) & 1][0];
                EPI_GROUP(accB, xvB, hwB, hstB, (float*)0);
                hstB += 65536;
            }
            #pragma unroll
            for (int j = 0; j < 8; ++j) {
                accA[j] = __builtin_amdgcn_mfma_i32_16x16x64_i8(wa[j][0], bfr[0], z4, 0, 0, 0);
                #pragma unroll
                for (int kt = 1; kt < 7; ++kt)
                    accA[j] = __builtin_amdgcn_mfma_i32_16x16x64_i8(wa[j][kt], bfr[kt], accA[j], 0, 0, 0);
                accA[j] = __builtin_amdgcn_mfma_i32_16x16x64_i8(wv[j], bfr[7], accA[j], 0, 0, 0);
            }
            lds_barrier();
        }
    }

    // ---- drain: epi_B(511) ----
    {
        unsigned char* hwB = &h2[1][0][0];   // dead write, keeps macro uniform
        float* hlB = (MODE == 1) ? (h_last + (size_t)bbB * 512) : (float*)0;
        EPI_GROUP(accB, xvB, hwB, hstB, hlB);
    }
}

// ---------------------------------------------------------------------------
// head: logits[b][c] = h_last[b][:]·W_out[c][:] + b_out[c]; log_softmax rows.
// ---------------------------------------------------------------------------
__global__ __launch_bounds__(256, 2) void head_kernel(
    const float* __restrict__ hl, const float* __restrict__ Wout,
    const float* __restrict__ bout, float* __restrict__ out)
{
    __shared__ float hrow[512];
    __shared__ float lg[1000];
    __shared__ float red[8];
    const int b = blockIdx.x, tid = threadIdx.x;

    hrow[tid]       = hl[(size_t)b * 512 + tid];
    hrow[tid + 256] = hl[(size_t)b * 512 + 256 + tid];
    __syncthreads();

    float lmax = -1e30f;
    for (int c = tid; c < 1000; c += 256) {
        const float4* w4 = (const float4*)(Wout + (size_t)c * 512);
        float a0 = 0.f, a1 = 0.f, a2 = 0.f, a3 = 0.f;
        #pragma unroll 4
        for (int k = 0; k < 128; ++k) {
            float4 w = w4[k];
            a0 += hrow[4 * k + 0] * w.x;
            a1 += hrow[4 * k + 1] * w.y;
            a2 += hrow[4 * k + 2] * w.z;
            a3 += hrow[4 * k + 3] * w.w;
        }
        float acc = bout[c] + (a0 + a1) + (a2 + a3);
        lg[c] = acc;
        lmax = fmaxf(lmax, acc);
    }
    #pragma unroll
    for (int off = 32; off; off >>= 1) lmax = fmaxf(lmax, __shfl_down(lmax, off, 64));
    if ((tid & 63) == 0) red[tid >> 6] = lmax;
    __syncthreads();
    if (tid == 0) red[4] = fmaxf(fmaxf(red[0], red[1]), fmaxf(red[2], red[3]));
    __syncthreads();
    const float M = red[4];

    float lsum = 0.f;
    for (int c = tid; c < 1000; c += 256) lsum += __expf(lg[c] - M);
    #pragma unroll
    for (int off = 32; off; off >>= 1) lsum += __shfl_down(lsum, off, 64);
    __syncthreads();
    if ((tid & 63) == 0) red[tid >> 6] = lsum;
    __syncthreads();
    if (tid == 0) red[5] = M + __logf(red[0] + red[1] + red[2] + red[3]);
    __syncthreads();
    const float lse = red[5];

    for (int c = tid; c < 1000; c += 256)
        out[(size_t)b * 1000 + c] = lg[c] - lse;
}

// ---------------------------------------------------------------------------
extern "C" void kernel_launch(void* const* d_in, const int* in_sizes, int n_in,
                              void* d_out, int out_size, void* d_ws, size_t ws_size,
                              hipStream_t stream)
{
    const float* x    = (const float*)d_in[0];
    const float* Wih0 = (const float*)d_in[1];
    const float* Whh0 = (const float*)d_in[2];
    const float* bih0 = (const float*)d_in[3];
    const float* bhh0 = (const float*)d_in[4];
    const float* Wih1 = (const float*)d_in[5];
    const float* Whh1 = (const float*)d_in[6];
    const float* bih1 = (const float*)d_in[7];
    const float* bhh1 = (const float*)d_in[8];
    const float* Wout = (const float*)d_in[9];
    const float* bout = (const float*)d_in[10];
    float* out = (float*)d_out;

    char* ws = (char*)d_ws;
    unsigned short* bufA = (unsigned short*)ws;                              // 64 MB
    unsigned short* bufB = (unsigned short*)(ws + (size_t)64 * 1024 * 1024);
    signed char* Wq0 = (signed char*)bufB;                                   // 256 KB (dead after rec0)
    float*       sc0 = (float*)((char*)bufB + 262144);                       // 2 KB
    signed char* Wq1 = (signed char*)bufA;                                   // 256 KB (after proj1 consumed bufA)
    float*       sc1 = (float*)(ws + 262144);                                // 2 KB
    float*     hlast = (float*)(ws + (size_t)1 * 1024 * 1024);               // 256 KB

    const dim3 pgrid(8, 512);

    packi8_kernel<<<512, 64, 0, stream>>>(Whh0, Wq0, sc0);
    proj_kernel<128, 0><<<pgrid, 256, 0, stream>>>((const void*)x, Wih0, bih0, bhh0, bufA, TWO_LOG2E);
    rec9_kernel<0><<<4, 256, 0, stream>>>(Wq0, sc0, bufA, bufA, hlast);

    proj_kernel<512, 1><<<pgrid, 256, 0, stream>>>((const void*)bufA, Wih1, bih1, bhh1, bufB, TWO_LOG2E);
    packi8_kernel<<<512, 64, 0, stream>>>(Whh1, Wq1, sc1);
    rec9_kernel<1><<<4, 256, 0, stream>>>(Wq1, sc1, bufB, bufB, hlast);

    head_kernel<<<128, 256, 0, stream>>>(hlast, Wout, bout, out);
}

// Round 10
// 1990.187 us; speedup vs baseline: 1.6754x; 1.6754x over previous
//
#include <hip/hip_runtime.h>

// ============================================================================
// 2-layer tanh RNN (B=128,S=512,IN=128,H=512) + linear head (C=1000) + logsoftmax
//
// Round-10: R7 i8 recurrence (best: 928 us/layer) + latency surgery.
//   R7 step = 4350 cyc: ~2090 busy (VALU 700 + trans 510 + MFMA 900, near the
//   issue floor) + ~2250 stall. Stall sources: (1) xv loads consumed ~400 cyc
//   after issue but xp stream is HBM-cold (~900 cyc); (2) epilogue after all
//   64 MFMAs -> 8-deep MFMA dependency chains run empty.
//   Fixes (structure otherwise identical to R7 — 8 WGs x 256 thr, 1 wave/SIMD,
//   full W_hh i8 in 256 AGPRs, h i8 LDS dbuf, lgkm-only barrier):
//   - xv double-buffered, prefetched ONE FULL STEP ahead.
//   - source order: MFMA(j) ; epi(j-1) — fills each chain's latency.
//   - t-loop unrolled x2 -> LDS addresses loop-invariant (parity in imm).
//   - R9's proven numerics: proj pre-scales xp by 2*log2(e); sc2 absorbs it;
//     xv bf16->f32 via v_perm.
//
// ws layout: bufA = ws (64 MB): xp0/hs0 in place; later Wq1 head + hlast @
//            +1MB. bufB = ws+64MB: Wq0/sc0 head (dead after rec0), later xp1.
// ============================================================================

using short8  = __attribute__((ext_vector_type(8))) short;
using floatx4 = __attribute__((ext_vector_type(4))) float;
using i32x4   = __attribute__((ext_vector_type(4))) int;
using f32x4   = __attribute__((ext_vector_type(4))) float;

#define DEV static __device__ __forceinline__
#define PINA(x) asm volatile("" : "+a"(x))
#define PINV(x) asm volatile("" : "+v"(x))

#define TWO_LOG2E 2.8853900817779268f

DEV void lds_barrier() {
    // LDS-only barrier: do NOT drain vmcnt (global stores/loads keep flying).
    asm volatile("s_waitcnt lgkmcnt(0)\n\ts_barrier" ::: "memory");
}

DEV unsigned short f2bf(float f) {
    union { float f; unsigned u; } v; v.f = f;
    unsigned r = (v.u + 0x7fffu + ((v.u >> 16) & 1u)) >> 16;
    return (unsigned short)r;
}

// ---------------------------------------------------------------------------
// packi8: one block (64 thr) per W row j. Row absmax -> per-row scale;
// quantize to i8 in A-frag layout for mfma_i32_16x16x64_i8.
// sc2[j] = mx_j / 127^2 * 2*log2(e)  (dequant folded into exp2 argument).
// ---------------------------------------------------------------------------
__global__ __launch_bounds__(64) void packi8_kernel(
    const float* __restrict__ W, signed char* __restrict__ Wq,
    float* __restrict__ sc2)
{
    const int j = blockIdx.x;            // 0..511
    const int t = threadIdx.x;           // 0..63
    const float* row = W + (size_t)j * 512;

    float4 a = *(const float4*)(row + t * 8);
    float4 b = *(const float4*)(row + t * 8 + 4);
    float m = fmaxf(fmaxf(fabsf(a.x), fabsf(a.y)), fmaxf(fabsf(a.z), fabsf(a.w)));
    m = fmaxf(m, fmaxf(fmaxf(fabsf(b.x), fabsf(b.y)), fmaxf(fabsf(b.z), fabsf(b.w))));
    #pragma unroll
    for (int off = 32; off; off >>= 1) m = fmaxf(m, __shfl_down(m, off, 64));
    m = __shfl(m, 0, 64);
    if (t == 0) sc2[j] = m * (1.0f / (127.f * 127.f)) * TWO_LOG2E;

    if (t < 32) {
        const int kt = t >> 2, lq = t & 3;
        const int jtg = j >> 4, lm = j & 15;
        const float r = 127.f / m;
        int w4[4];
        #pragma unroll
        for (int w = 0; w < 4; ++w) {
            int v = 0;
            #pragma unroll
            for (int e = 0; e < 4; ++e) {
                int q = __float2int_rn(row[kt * 64 + lq * 16 + w * 4 + e] * r);
                v |= (q & 255) << (8 * e);
            }
            w4[w] = v;
        }
        i32x4 pk; pk[0] = w4[0]; pk[1] = w4[1]; pk[2] = w4[2]; pk[3] = w4[3];
        *(i32x4*)(Wq + ((size_t)((jtg * 8 + kt) * 64 + lq * 16 + lm)) * 16) = pk;
    }
}

// ---------------------------------------------------------------------------
// proj: out[m=t*128+b][n] = bf16( (A[m][:]·W[n][:] + b1[n]+b2[n]) * oscale )
// oscale = 2*log2(e): rec consumes xp only inside exp2 arguments.
// ---------------------------------------------------------------------------
template <int K, int MODE>
__global__ __launch_bounds__(256, 2) void proj_kernel(
    const void* __restrict__ Aptr, const float* __restrict__ W,
    const float* __restrict__ b1, const float* __restrict__ b2,
    unsigned short* __restrict__ out, float oscale)
{
    constexpr int LDA = 40;
    __shared__ unsigned short As[128 * LDA];
    __shared__ unsigned short Ws[64 * LDA];

    const int tid  = threadIdx.x;
    const int lane = tid & 63, wave = tid >> 6;
    const int lm   = lane & 15, lq = lane >> 4;
    const int nbase = blockIdx.x * 64;
    const int mtile = blockIdx.y;
    const int mbase = mtile * 128;

    floatx4 acc[2][4] = {};

    const int ar = tid >> 1, ak = (tid & 1) * 16;
    const int wr = tid >> 2, wk = (tid & 3) * 8;

    for (int k0 = 0; k0 < K; k0 += 32) {
        if (MODE == 0) {
            const float* x   = (const float*)Aptr;
            const float* src = x + ((size_t)ar * 512 + mtile) * 128 + (k0 + ak);
            float4 f0 = *(const float4*)(src + 0);
            float4 f1 = *(const float4*)(src + 4);
            float4 f2 = *(const float4*)(src + 8);
            float4 f3 = *(const float4*)(src + 12);
            unsigned short* d = As + ar * LDA + ak;
            d[0]=f2bf(f0.x); d[1]=f2bf(f0.y); d[2]=f2bf(f0.z); d[3]=f2bf(f0.w);
            d[4]=f2bf(f1.x); d[5]=f2bf(f1.y); d[6]=f2bf(f1.z); d[7]=f2bf(f1.w);
            d[8]=f2bf(f2.x); d[9]=f2bf(f2.y); d[10]=f2bf(f2.z); d[11]=f2bf(f2.w);
            d[12]=f2bf(f3.x); d[13]=f2bf(f3.y); d[14]=f2bf(f3.z); d[15]=f2bf(f3.w);
        } else {
            const unsigned short* h =
                (const unsigned short*)Aptr + (size_t)(mbase + ar) * K + k0 + ak;
            short8 v0 = *(const short8*)(h);
            short8 v1 = *(const short8*)(h + 8);
            *(short8*)(As + ar * LDA + ak)     = v0;
            *(short8*)(As + ar * LDA + ak + 8) = v1;
        }
        {
            const float* src = W + (size_t)(nbase + wr) * K + k0 + wk;
            float4 f0 = *(const float4*)(src);
            float4 f1 = *(const float4*)(src + 4);
            unsigned short* d = Ws + wr * LDA + wk;
            d[0]=f2bf(f0.x); d[1]=f2bf(f0.y); d[2]=f2bf(f0.z); d[3]=f2bf(f0.w);
            d[4]=f2bf(f1.x); d[5]=f2bf(f1.y); d[6]=f2bf(f1.z); d[7]=f2bf(f1.w);
        }
        __syncthreads();

        short8 af0 = *(const short8*)(As + (wave * 32 +  0 + lm) * LDA + lq * 8);
        short8 af1 = *(const short8*)(As + (wave * 32 + 16 + lm) * LDA + lq * 8);
        #pragma unroll
        for (int nt = 0; nt < 4; ++nt) {
            short8 bf = *(const short8*)(Ws + (nt * 16 + lm) * LDA + lq * 8);
            acc[0][nt] = __builtin_amdgcn_mfma_f32_16x16x32_bf16(af0, bf, acc[0][nt], 0, 0, 0);
            acc[1][nt] = __builtin_amdgcn_mfma_f32_16x16x32_bf16(af1, bf, acc[1][nt], 0, 0, 0);
        }
        __syncthreads();
    }

    #pragma unroll
    for (int nt = 0; nt < 4; ++nt) {
        const int n = nbase + nt * 16 + lm;
        const float bias = b1[n] + b2[n];
        #pragma unroll
        for (int mt = 0; mt < 2; ++mt) {
            const int mrow = mbase + wave * 32 + mt * 16 + lq * 4;
            #pragma unroll
            for (int r = 0; r < 4; ++r)
                out[(size_t)(mrow + r) * 512 + n] = f2bf((acc[mt][nt][r] + bias) * oscale);
        }
    }
}

// ---------------------------------------------------------------------------
// rec10: 8 WGs x 256 thr (4 waves, 1/SIMD). WG bg owns batches [bg*16,+16),
// full H=512; wave owns 8 j-tiles. Full W_hh(i8) in 256 AGPRs.
// h state: i8 LDS [2][16 b][512 j], 16B-granule swizzle g' = g ^ lm.
// j-pipelined: MFMA(j) ; epi(j-1). xv prefetched one full step ahead.
// MODE 0: store h_t bf16 to hs_out (in-place over xp). MODE 1: t=511 -> h_last.
// ---------------------------------------------------------------------------

#define MFMA_J(JJ, BFR)                                                        \
  {                                                                            \
    acc[JJ] = __builtin_amdgcn_mfma_i32_16x16x64_i8(wa[JJ][0], BFR[0], z4, 0, 0, 0); \
    _Pragma("unroll")                                                          \
    for (int kt = 1; kt < 8; ++kt)                                             \
      acc[JJ] = __builtin_amdgcn_mfma_i32_16x16x64_i8(wa[JJ][kt], BFR[kt], acc[JJ], 0, 0, 0); \
  }

#define EPI_J(JJ, XVROW, HWBUF, TCUR)                                          \
  {                                                                            \
    const int jtg = wave * 8 + (JJ);                                           \
    float x0 = __uint_as_float(__builtin_amdgcn_perm(XVROW[JJ].x, 0u, 0x05040c0cu)); \
    float x1 = __uint_as_float(__builtin_amdgcn_perm(XVROW[JJ].x, 0u, 0x07060c0cu)); \
    float x2 = __uint_as_float(__builtin_amdgcn_perm(XVROW[JJ].y, 0u, 0x05040c0cu)); \
    float x3 = __uint_as_float(__builtin_amdgcn_perm(XVROW[JJ].y, 0u, 0x07060c0cu)); \
    float e0 = __builtin_amdgcn_exp2f(fmaf((float)acc[JJ][0], sc[JJ][0], x0));  \
    float e1 = __builtin_amdgcn_exp2f(fmaf((float)acc[JJ][1], sc[JJ][1], x1));  \
    float e2 = __builtin_amdgcn_exp2f(fmaf((float)acc[JJ][2], sc[JJ][2], x2));  \
    float e3 = __builtin_amdgcn_exp2f(fmaf((float)acc[JJ][3], sc[JJ][3], x3));  \
    float q0 = fmaf(-2.f, __builtin_amdgcn_rcpf(e0 + 1.f), 1.f);                \
    float q1 = fmaf(-2.f, __builtin_amdgcn_rcpf(e1 + 1.f), 1.f);                \
    float q2 = fmaf(-2.f, __builtin_amdgcn_rcpf(e2 + 1.f), 1.f);                \
    float q3 = fmaf(-2.f, __builtin_amdgcn_rcpf(e3 + 1.f), 1.f);                \
    unsigned m0 = __float_as_uint(fmaf(q0, 127.f, 12582912.f));                 \
    unsigned m1 = __float_as_uint(fmaf(q1, 127.f, 12582912.f));                 \
    unsigned m2 = __float_as_uint(fmaf(q2, 127.f, 12582912.f));                 \
    unsigned m3 = __float_as_uint(fmaf(q3, 127.f, 12582912.f));                 \
    unsigned lo = __builtin_amdgcn_perm(m1, m0, 0x00000400u);                   \
    unsigned hi = __builtin_amdgcn_perm(m3, m2, 0x00000400u);                   \
    unsigned qb = __builtin_amdgcn_perm(hi, lo, 0x05040100u);                   \
    *(unsigned*)((HWBUF) + lm * 512 + ((jtg ^ lm) << 4) + lq * 4) = qb;         \
    if (MODE == 0) {                                                            \
      uint2 st;                                                                 \
      st.x = __builtin_amdgcn_perm(__float_as_uint(q1), __float_as_uint(q0), 0x07060302u); \
      st.y = __builtin_amdgcn_perm(__float_as_uint(q3), __float_as_uint(q2), 0x07060302u); \
      *(uint2*)(hst + (JJ) * 16) = st;                                          \
    } else if ((TCUR) == 511) {                                                 \
      float4 o; o.x = q0; o.y = q1; o.z = q2; o.w = q3;                         \
      *(float4*)(h_last + (size_t)bb * 512 + jtg * 16 + lq * 4) = o;            \
    }                                                                           \
  }

#define REC_STEP(P, TCUR)                                                      \
  {                                                                            \
    i32x4 bfr[8];                                                              \
    _Pragma("unroll")                                                          \
    for (int kt = 0; kt < 8; ++kt)                                             \
      bfr[kt] = *(const i32x4*)(&h2[P][0] + lm * 512 + ((((kt << 2) + lq)) ^ lm) * 16); \
    if ((TCUR) < 511) {                                                        \
      _Pragma("unroll")                                                        \
      for (int j = 0; j < 8; ++j)                                              \
        xv[(P) ^ 1][j] = *(const uint2*)(xpt + j * 16);                        \
      xpt += 65536;                                                            \
    }                                                                          \
    MFMA_J(0, bfr);                                                            \
    _Pragma("unroll")                                                          \
    for (int j = 1; j < 8; ++j) {                                              \
      MFMA_J(j, bfr);                                                          \
      EPI_J(j - 1, xv[P], &h2[(P) ^ 1][0], TCUR);                              \
    }                                                                          \
    EPI_J(7, xv[P], &h2[(P) ^ 1][0], TCUR);                                    \
    if (MODE == 0) hst += 65536;                                               \
    lds_barrier();                                                             \
  }

template <int MODE>
__global__ __launch_bounds__(256, 1) void rec10_kernel(
    const signed char* __restrict__ Wq,   // [32 jtg][8 kt][64 lane][16] i8
    const float* __restrict__ sc2,        // [512] row scale * 2log2e / 127^2
    const unsigned short* xp,             // [S][B][H] bf16 SCALED (aliases hs_out)
    unsigned short* hs_out,               // [S][B][H] bf16
    float* __restrict__ h_last)           // [B][H] fp32
{
    __shared__ unsigned char h2[2][16 * 512];   // 16 KB

    const int tid  = threadIdx.x;
    const int lane = tid & 63;
    const int wave = tid >> 6;              // 0..3
    const int lm   = lane & 15, lq = lane >> 4;
    const int bg   = blockIdx.x;
    const int bb   = bg * 16 + lm;

    // ---- full W slice in AGPRs: 8 jtg x 8 kt x int4 = 256 AGPRs ----
    i32x4 wa[8][8];
    #pragma unroll
    for (int j = 0; j < 8; ++j) {
        const int jtg = wave * 8 + j;
        #pragma unroll
        for (int kt = 0; kt < 8; ++kt)
            wa[j][kt] = *(const i32x4*)(Wq + ((size_t)((jtg * 8 + kt) * 64 + lane)) * 16);
    }
    #pragma unroll
    for (int j = 0; j < 8; ++j)
        #pragma unroll
        for (int kt = 0; kt < 8; ++kt)
            PINA(wa[j][kt]);

    // ---- per-lane fused dequant scales, pinned ----
    f32x4 sc[8];
    #pragma unroll
    for (int j = 0; j < 8; ++j)
        sc[j] = *(const f32x4*)(sc2 + (wave * 8 + j) * 16 + lq * 4);
    #pragma unroll
    for (int j = 0; j < 8; ++j) PINV(sc[j]);

    // ---- zero h buffers ----
    for (int i = tid; i < 4096; i += 256) ((int*)h2)[i] = 0;
    __syncthreads();

    // per-thread streaming pointers (row stride 128*512 elems per step)
    const unsigned short* xpt = xp + (size_t)bb * 512 + wave * 128 + lq * 4;
    unsigned short*       hst = hs_out + (size_t)bb * 512 + wave * 128 + lq * 4;

    uint2 xv[2][8];
    i32x4 acc[8];
    const i32x4 z4 = {0, 0, 0, 0};

    // ---- prologue: xv[0] = row 0 ----
    #pragma unroll
    for (int j = 0; j < 8; ++j) xv[0][j] = *(const uint2*)(xpt + j * 16);
    xpt += 65536;

    for (int t = 0; t < 512; t += 2) {
        REC_STEP(0, t);
        REC_STEP(1, t + 1);
    }
}

// ---------------------------------------------------------------------------
// head: logits[b][c] = h_last[b][:]·W_out[c][:] + b_out[c]; log_softmax rows.
// ---------------------------------------------------------------------------
__global__ __launch_bounds__(256, 2) void head_kernel(
    const float* __restrict__ hl, const float* __restrict__ Wout,
    const float* __restrict__ bout, float* __restrict__ out)
{
    __shared__ float hrow[512];
    __shared__ float lg[1000];
    __shared__ float red[8];
    const int b = blockIdx.x, tid = threadIdx.x;

    hrow[tid]       = hl[(size_t)b * 512 + tid];
    hrow[tid + 256] = hl[(size_t)b * 512 + 256 + tid];
    __syncthreads();

    float lmax = -1e30f;
    for (int c = tid; c < 1000; c += 256) {
        const float4* w4 = (const float4*)(Wout + (size_t)c * 512);
        float a0 = 0.f, a1 = 0.f, a2 = 0.f, a3 = 0.f;
        #pragma unroll 4
        for (int k = 0; k < 128; ++k) {
            float4 w = w4[k];
            a0 += hrow[4 * k + 0] * w.x;
            a1 += hrow[4 * k + 1] * w.y;
            a2 += hrow[4 * k + 2] * w.z;
            a3 += hrow[4 * k + 3] * w.w;
        }
        float acc = bout[c] + (a0 + a1) + (a2 + a3);
        lg[c] = acc;
        lmax = fmaxf(lmax, acc);
    }
    #pragma unroll
    for (int off = 32; off; off >>= 1) lmax = fmaxf(lmax, __shfl_down(lmax, off, 64));
    if ((tid & 63) == 0) red[tid >> 6] = lmax;
    __syncthreads();
    if (tid == 0) red[4] = fmaxf(fmaxf(red[0], red[1]), fmaxf(red[2], red[3]));
    __syncthreads();
    const float M = red[4];

    float lsum = 0.f;
    for (int c = tid; c < 1000; c += 256) lsum += __expf(lg[c] - M);
    #pragma unroll
    for (int off = 32; off; off >>= 1) lsum += __shfl_down(lsum, off, 64);
    __syncthreads();
    if ((tid & 63) == 0) red[tid >> 6] = lsum;
    __syncthreads();
    if (tid == 0) red[5] = M + __logf(red[0] + red[1] + red[2] + red[3]);
    __syncthreads();
    const float lse = red[5];

    for (int c = tid; c < 1000; c += 256)
        out[(size_t)b * 1000 + c] = lg[c] - lse;
}

// ---------------------------------------------------------------------------
extern "C" void kernel_launch(void* const* d_in, const int* in_sizes, int n_in,
                              void* d_out, int out_size, void* d_ws, size_t ws_size,
                              hipStream_t stream)
{
    const float* x    = (const float*)d_in[0];
    const float* Wih0 = (const float*)d_in[1];
    const float* Whh0 = (const float*)d_in[2];
    const float* bih0 = (const float*)d_in[3];
    const float* bhh0 = (const float*)d_in[4];
    const float* Wih1 = (const float*)d_in[5];
    const float* Whh1 = (const float*)d_in[6];
    const float* bih1 = (const float*)d_in[7];
    const float* bhh1 = (const float*)d_in[8];
    const float* Wout = (const float*)d_in[9];
    const float* bout = (const float*)d_in[10];
    float* out = (float*)d_out;

    char* ws = (char*)d_ws;
    unsigned short* bufA = (unsigned short*)ws;                              // 64 MB
    unsigned short* bufB = (unsigned short*)(ws + (size_t)64 * 1024 * 1024);
    signed char* Wq0 = (signed char*)bufB;                                   // 256 KB (dead after rec0)
    float*       sc0 = (float*)((char*)bufB + 262144);                       // 2 KB
    signed char* Wq1 = (signed char*)bufA;                                   // 256 KB (after proj1 consumed bufA)
    float*       sc1 = (float*)(ws + 262144);                                // 2 KB
    float*     hlast = (float*)(ws + (size_t)1 * 1024 * 1024);               // 256 KB

    const dim3 pgrid(8, 512);

    packi8_kernel<<<512, 64, 0, stream>>>(Whh0, Wq0, sc0);
    proj_kernel<128, 0><<<pgrid, 256, 0, stream>>>((const void*)x, Wih0, bih0, bhh0, bufA, TWO_LOG2E);
    rec10_kernel<0><<<8, 256, 0, stream>>>(Wq0, sc0, bufA, bufA, hlast);

    proj_kernel<512, 1><<<pgrid, 256, 0, stream>>>((const void*)bufA, Wih1, bih1, bhh1, bufB, TWO_LOG2E);
    packi8_kernel<<<512, 64, 0, stream>>>(Whh1, Wq1, sc1);
    rec10_kernel<1><<<8, 256, 0, stream>>>(Wq1, sc1, bufB, bufB, hlast);

    head_kernel<<<128, 256, 0, stream>>>(hlast, Wout, bout, out);
}